// Round 10
// baseline (229.822 us; speedup 1.0000x reference)
//
#include <hip/hip_runtime.h>
#include <math.h>

#define CH   128
#define NSP  4096
#define BATCH 4
#define BIG  (BATCH*NSP*CH)   // 2,097,152 elements per (B,N,C) buffer
#define KCHUNKS 16            // split-K chunks for chscore (256 n-rows each)
#define FKSPLIT 6             // split-K for flash (11,11,11,11,10,10 x 64-row tiles)
#define MB (1024*1024)

typedef short short8 __attribute__((ext_vector_type(8)));
typedef float floatx4 __attribute__((ext_vector_type(4)));

__device__ __forceinline__ unsigned short f2bu(float f) {
  union { float f; unsigned u; } v; v.f = f;
  unsigned r = v.u + 0x7fffu + ((v.u >> 16) & 1u);
  return (unsigned short)(r >> 16);
}
__device__ __forceinline__ float b2f(unsigned short h) {
  union { unsigned u; float f; } v; v.u = ((unsigned)h) << 16;
  return v.f;
}

// ---------------- LayerNorm over channels → xfb bf16 ----------------
__global__ __launch_bounds__(256) void ln_kernel(const float* __restrict__ x,
    const float* __restrict__ g, const float* __restrict__ bta,
    unsigned short* __restrict__ xfb) {
  __shared__ float tile[128][65];
  __shared__ float pS[4][64];
  __shared__ float pQ[4][64];
  __shared__ float mu_s[64], rs_s[64];
  int t = threadIdx.x;
  int b  = blockIdx.x >> 6;
  int n0 = (blockIdx.x & 63) << 6;
  for (int i = t; i < 8192; i += 256) {
    int c = i >> 6, n = i & 63;
    tile[c][n] = x[(size_t)(b*CH + c)*NSP + n0 + n];
  }
  __syncthreads();
  {
    int n = t & 63, part = t >> 6;
    float s = 0.f, qq = 0.f;
    for (int c = part; c < 128; c += 4) { float v = tile[c][n]; s += v; qq += v*v; }
    pS[part][n] = s; pQ[part][n] = qq;
  }
  __syncthreads();
  if (t < 64) {
    float s = pS[0][t] + pS[1][t] + pS[2][t] + pS[3][t];
    float qq = pQ[0][t] + pQ[1][t] + pQ[2][t] + pQ[3][t];
    float mu = s * (1.f/128.f);
    float var = qq * (1.f/128.f) - mu*mu;
    mu_s[t] = mu;
    rs_s[t] = rsqrtf(var + 1e-5f);
  }
  __syncthreads();
  for (int i = t; i < 8192; i += 256) {
    int n = i >> 7, c = i & 127;
    float v = (tile[c][n] - mu_s[n]) * rs_s[n] * g[c] + bta[c];
    xfb[(size_t)(b*NSP + n0 + n)*CH + c] = f2bu(v);
  }
}

// ---------------- pooled = mean over spatial → (B,C) ----------------
__global__ __launch_bounds__(256) void pooled_kernel(const float* __restrict__ x,
                                                     float* __restrict__ pooled) {
  int bc = blockIdx.x; int t = threadIdx.x;
  const float4* p = (const float4*)(x + (size_t)bc*NSP);
  float s = 0.f;
  for (int i = t; i < 1024; i += 256) { float4 v = p[i]; s += v.x+v.y+v.z+v.w; }
  for (int off = 32; off; off >>= 1) s += __shfl_xor(s, off, 64);
  __shared__ float red[4];
  if ((t & 63) == 0) red[t >> 6] = s;
  __syncthreads();
  if (t == 0) pooled[bc] = (red[0]+red[1]+red[2]+red[3]) * (1.f/4096.f);
}

// ---------------- gate weights ----------------
__global__ void gate_kernel(const float* __restrict__ pooled, const float* __restrict__ Wg,
                            const float* __restrict__ bg, float* __restrict__ wgt) {
  __shared__ float lg[4][3];
  int t = threadIdx.x;
  if (t < 12) {
    int b = t / 3, j = t % 3;
    float s = bg[j];
    const float* pr = pooled + b*CH;
    const float* wr = Wg + j*CH;
    for (int c = 0; c < CH; ++c) s += pr[c]*wr[c];
    lg[b][j] = s;
  }
  __syncthreads();
  if (t < 4) {
    float a = lg[t][0], b2 = lg[t][1], c = lg[t][2];
    float m = fmaxf(a, fmaxf(b2, c));
    float e0 = __expf(a-m), e1 = __expf(b2-m), e2 = __expf(c-m);
    float inv = 1.f/(e0+e1+e2);
    wgt[t*3+0] = e0*inv; wgt[t*3+1] = e1*inv; wgt[t*3+2] = e2*inv;
  }
}

// ---------------- Conv3d C->2, k=3, SAME — wave-cluster reduction ----------------
__global__ __launch_bounds__(256) void conv_kernel(const unsigned short* __restrict__ xfb,
    const float* __restrict__ Wc, const float* __restrict__ bc_, float* __restrict__ cgf) {
  __shared__ float Wl[27*256];                 // [tap][o][c] = 27.6 KB
  int t = threadIdx.x;
  for (int i = t; i < 6912; i += 256) {
    int tap = i >> 8;
    int rem = i & 255;
    int o = rem >> 7, c = rem & 127;
    Wl[i] = Wc[o*3456 + c*27 + tap];
  }
  __syncthreads();
  int cg = t & 15, spl = t >> 4;
  int sp = blockIdx.x*16 + spl;                // 0..16383
  int b = sp >> 12, n = sp & 4095;
  int z = n >> 8, y = (n >> 4) & 15, xw = n & 15;
  const unsigned short* xb = xfb + (size_t)b*NSP*CH + cg*8;
  float a0 = 0.f, a1 = 0.f;
  for (int kd = 0; kd < 3; ++kd) {
    int zz = z + kd - 1; if ((unsigned)zz >= 16u) continue;
    for (int kh = 0; kh < 3; ++kh) {
      int yy = y + kh - 1; if ((unsigned)yy >= 16u) continue;
      #pragma unroll
      for (int kw = 0; kw < 3; ++kw) {
        int xx = xw + kw - 1; if ((unsigned)xx >= 16u) continue;
        int nn = (zz << 8) + (yy << 4) + xx;
        short8 xv = *(const short8*)(xb + (size_t)nn*CH);
        int tap = (kd*3 + kh)*3 + kw;
        const float* wbase = &Wl[tap*256 + cg*8];
        float4 w00 = *(const float4*)(wbase);
        float4 w01 = *(const float4*)(wbase + 4);
        float4 w10 = *(const float4*)(wbase + 128);
        float4 w11 = *(const float4*)(wbase + 132);
        float x0 = b2f((unsigned short)xv[0]), x1 = b2f((unsigned short)xv[1]);
        float x2 = b2f((unsigned short)xv[2]), x3 = b2f((unsigned short)xv[3]);
        float x4 = b2f((unsigned short)xv[4]), x5 = b2f((unsigned short)xv[5]);
        float x6 = b2f((unsigned short)xv[6]), x7 = b2f((unsigned short)xv[7]);
        a0 += x0*w00.x + x1*w00.y + x2*w00.z + x3*w00.w
            + x4*w01.x + x5*w01.y + x6*w01.z + x7*w01.w;
        a1 += x0*w10.x + x1*w10.y + x2*w10.z + x3*w10.w
            + x4*w11.x + x5*w11.y + x6*w11.z + x7*w11.w;
      }
    }
  }
  #pragma unroll
  for (int off = 1; off <= 8; off <<= 1) {
    a0 += __shfl_xor(a0, off, 64);
    a1 += __shfl_xor(a1, off, 64);
  }
  if (cg == 0) {
    cgf[b*8192 + n]        = a0 + bc_[0];
    cgf[b*8192 + 4096 + n] = a1 + bc_[1];
  }
}

// ---------------- MFMA projection: Y = X W^T + b (fp32 W converted in staging) ----------------
__global__ __launch_bounds__(256) void proj_mfma_kernel(
    const unsigned short* __restrict__ xfb,
    const float* __restrict__ Wq, const float* __restrict__ Wk,
    const float* __restrict__ Wvc, const float* __restrict__ Wvch,
    const float* __restrict__ bq, const float* __restrict__ bk,
    const float* __restrict__ bvc, const float* __restrict__ bvch,
    unsigned short* __restrict__ q, unsigned short* __restrict__ k,
    unsigned short* __restrict__ vc, unsigned short* __restrict__ vch) {
  __shared__ __align__(16) unsigned short Ws[128][136];
  int t = threadIdx.x;
  int lane = t & 63, w = t >> 6;
  int id = lane & 15, quad = lane >> 4;
  int pj = blockIdx.y;
  int r0 = blockIdx.x*128 + w*32;

  const float* Wp = (pj == 0) ? Wq : (pj == 1) ? Wk : (pj == 2) ? Wvc : Wvch;
  for (int i = t; i < 2048; i += 256) {
    int rr = i >> 4, c8 = (i & 15) << 3;
    const float* src = Wp + rr*CH + c8;
    short8 pk;
    #pragma unroll
    for (int j = 0; j < 8; ++j) pk[j] = (short)f2bu(src[j]);
    *(short8*)&Ws[rr][c8] = pk;
  }
  short8 af[2][4];
  #pragma unroll
  for (int m = 0; m < 2; ++m)
    #pragma unroll
    for (int kc = 0; kc < 4; ++kc)
      af[m][kc] = *(const short8*)(xfb + (size_t)(r0 + m*16 + id)*CH + kc*32 + quad*8);
  __syncthreads();

  floatx4 acc[2][8];
  #pragma unroll
  for (int m = 0; m < 2; ++m)
    #pragma unroll
    for (int nt = 0; nt < 8; ++nt) acc[m][nt] = (floatx4){0.f,0.f,0.f,0.f};
  #pragma unroll
  for (int nt = 0; nt < 8; ++nt)
    #pragma unroll
    for (int kc = 0; kc < 4; ++kc) {
      short8 bf = *(const short8*)&Ws[nt*16 + id][kc*32 + quad*8];
      acc[0][nt] = __builtin_amdgcn_mfma_f32_16x16x32_bf16(af[0][kc], bf, acc[0][nt], 0, 0, 0);
      acc[1][nt] = __builtin_amdgcn_mfma_f32_16x16x32_bf16(af[1][kc], bf, acc[1][nt], 0, 0, 0);
    }

  const float* bias = (pj == 0) ? bq : (pj == 1) ? bk : (pj == 2) ? bvc : bvch;
  unsigned short* Y = (pj == 0) ? q : (pj == 1) ? k : (pj == 2) ? vc : vch;
  #pragma unroll
  for (int nt = 0; nt < 8; ++nt) {
    float bsv = bias[nt*16 + id];
    #pragma unroll
    for (int m = 0; m < 2; ++m)
      #pragma unroll
      for (int r = 0; r < 4; ++r) {
        int row = r0 + m*16 + quad*4 + r;
        Y[(size_t)row*CH + nt*16 + id] = f2bu(acc[m][nt][r] + bsv);
      }
  }
}

// ---------------- transpose vc (B,N,C) -> vct (B,C,N), bf16 ----------------
__global__ __launch_bounds__(256) void vtrans_kernel(const unsigned short* __restrict__ vc,
                                                     unsigned short* __restrict__ vct) {
  __shared__ unsigned short T[128][72];   // [c][n], 64 n per tile
  int t = threadIdx.x;
  int b = blockIdx.x >> 6, n0 = (blockIdx.x & 63) << 6;
  for (int i = t; i < 1024; i += 256) {
    int n = i >> 4, c0 = (i & 15) << 3;
    short8 v = *(const short8*)&vc[(size_t)(b*NSP + n0 + n)*CH + c0];
    #pragma unroll
    for (int j = 0; j < 8; ++j) T[c0+j][n] = (unsigned short)v[j];
  }
  __syncthreads();
  for (int i = t; i < 1024; i += 256) {
    int c = i >> 3, k8 = (i & 7) << 3;
    *(short8*)&vct[((size_t)b*CH + c)*NSP + n0 + k8] = *(short8*)&T[c][k8];
  }
}

// ---------------- channel scores: split-K(16) MFMA, 4-stage loop. Sp[p][b][c][d] ----------------
__global__ __launch_bounds__(256) void chscore_kernel(const unsigned short* __restrict__ q,
    const unsigned short* __restrict__ k, float* __restrict__ Sp) {
  __shared__ unsigned short Qt[128][72];
  __shared__ unsigned short Kt[128][72];
  int t = threadIdx.x;
  int lane = t & 63, w = t >> 6;
  int id = lane & 15, quad = lane >> 4;
  int p = blockIdx.x;
  int b = blockIdx.y;
  const unsigned short* qb = q + (size_t)b*NSP*CH;
  const unsigned short* kb = k + (size_t)b*NSP*CH;

  floatx4 acc[2][8];
  #pragma unroll
  for (int mt = 0; mt < 2; ++mt)
    #pragma unroll
    for (int nt = 0; nt < 8; ++nt) acc[mt][nt] = (floatx4){0.f,0.f,0.f,0.f};

  for (int s = 0; s < 4; ++s) {
    int nbase = p*256 + s*64;
    __syncthreads();
    #pragma unroll
    for (int it = 0; it < 4; ++it) {
      int task = t + it*256;
      int c = task & 127, r0 = (task >> 7) << 3;
      short8 vq, vk;
      #pragma unroll
      for (int j = 0; j < 8; ++j) {
        size_t off = (size_t)(nbase + r0 + j)*CH + c;
        vq[j] = (short)qb[off];
        vk[j] = (short)kb[off];
      }
      *(short8*)&Qt[c][r0] = vq;
      *(short8*)&Kt[c][r0] = vk;
    }
    __syncthreads();
    #pragma unroll
    for (int kc = 0; kc < 2; ++kc) {
      short8 af0 = *(const short8*)&Qt[w*32 + id     ][kc*32 + quad*8];
      short8 af1 = *(const short8*)&Qt[w*32 + 16 + id][kc*32 + quad*8];
      #pragma unroll
      for (int nt = 0; nt < 8; ++nt) {
        short8 bf = *(const short8*)&Kt[nt*16 + id][kc*32 + quad*8];
        acc[0][nt] = __builtin_amdgcn_mfma_f32_16x16x32_bf16(af0, bf, acc[0][nt], 0, 0, 0);
        acc[1][nt] = __builtin_amdgcn_mfma_f32_16x16x32_bf16(af1, bf, acc[1][nt], 0, 0, 0);
      }
    }
  }
  float* outp = Sp + ((size_t)(p*BATCH + b) << 14);
  #pragma unroll
  for (int mt = 0; mt < 2; ++mt)
    #pragma unroll
    for (int nt = 0; nt < 8; ++nt)
      #pragma unroll
      for (int r = 0; r < 4; ++r) {
        int c = w*32 + mt*16 + quad*4 + r;
        int d = nt*16 + id;
        outp[c*CH + d] = acc[mt][nt][r];
      }
}

// reduce split-K partials + softmax over last axis, scale 1/64 → Schb (bf16)
__global__ __launch_bounds__(64) void chsoftmax_kernel(const float* __restrict__ Sp,
                                                       unsigned short* __restrict__ Sb) {
  int row = blockIdx.x;
  int b = row >> 7, c = row & 127;
  int t = threadIdx.x;
  float s0 = 0.f, s1 = 0.f;
  #pragma unroll 4
  for (int p = 0; p < KCHUNKS; ++p) {
    const float* r = Sp + (((size_t)(p*BATCH + b) << 7) + c)*CH;
    s0 += r[t]; s1 += r[t+64];
  }
  const float sc = 1.f/64.f;
  s0 *= sc; s1 *= sc;
  float m = fmaxf(s0, s1);
  for (int off = 32; off; off >>= 1) m = fmaxf(m, __shfl_xor(m, off, 64));
  float p0 = __expf(s0 - m), p1 = __expf(s1 - m);
  float s = p0 + p1;
  for (int off = 32; off; off >>= 1) s += __shfl_xor(s, off, 64);
  float inv = 1.f/s;
  unsigned short* r = Sb + (size_t)row*CH;
  r[t]    = f2bu(p0*inv);
  r[t+64] = f2bu(p1*inv);
}

// ---------------- channel-attention apply ----------------
__global__ __launch_bounds__(256) void chout_mfma_kernel(
    const unsigned short* __restrict__ vchb, const unsigned short* __restrict__ Sb,
    float* __restrict__ och) {
  __shared__ __align__(16) unsigned short As[128][136];
  int t = threadIdx.x;
  int lane = t & 63, w = t >> 6;
  int id = lane & 15, quad = lane >> 4;
  int b = blockIdx.x >> 5;
  int r0 = blockIdx.x*128 + w*32;

  const unsigned short* Sp = Sb + ((size_t)b << 14);
  for (int i = t; i < 2048; i += 256) {
    int rr = i >> 4, c8 = (i & 15) << 3;
    *(short8*)&As[rr][c8] = *(const short8*)(Sp + rr*CH + c8);
  }
  short8 af[2][4];
  #pragma unroll
  for (int m = 0; m < 2; ++m)
    #pragma unroll
    for (int kc = 0; kc < 4; ++kc)
      af[m][kc] = *(const short8*)(vchb + (size_t)(r0 + m*16 + id)*CH + kc*32 + quad*8);
  __syncthreads();

  floatx4 acc[2][8];
  #pragma unroll
  for (int m = 0; m < 2; ++m)
    #pragma unroll
    for (int nt = 0; nt < 8; ++nt) acc[m][nt] = (floatx4){0.f,0.f,0.f,0.f};
  #pragma unroll
  for (int nt = 0; nt < 8; ++nt)
    #pragma unroll
    for (int kc = 0; kc < 4; ++kc) {
      short8 bf = *(const short8*)&As[nt*16 + id][kc*32 + quad*8];
      acc[0][nt] = __builtin_amdgcn_mfma_f32_16x16x32_bf16(af[0][kc], bf, acc[0][nt], 0, 0, 0);
      acc[1][nt] = __builtin_amdgcn_mfma_f32_16x16x32_bf16(af[1][kc], bf, acc[1][nt], 0, 0, 0);
    }
  #pragma unroll
  for (int nt = 0; nt < 8; ++nt)
    #pragma unroll
    for (int m = 0; m < 2; ++m)
      #pragma unroll
      for (int r = 0; r < 4; ++r) {
        int row = r0 + m*16 + quad*4 + r;
        och[(size_t)row*CH + nt*16 + id] = acc[m][nt][r];
      }
}

// ---------------- flash partial: split-K x6, register-pipelined, XCD-pinned swizzle ----------------
// Grid 768 = 8 XCD-slots x 3 combos x 32 tiles. XCD x = blk&7 owns 3 (b,ks) combos,
// processed 32 consecutive blocks at a time -> each XCD's concurrent K/V working set is
// one combo's range (~350 KB), L2-resident. 3 blocks/CU co-resident (53.2 KB LDS x3).
__global__ __launch_bounds__(256) void flash_part_kernel(
    const unsigned short* __restrict__ Qg, const unsigned short* __restrict__ Kg,
    const unsigned short* __restrict__ Vtg,
    unsigned short* __restrict__ Opart, float* __restrict__ lpart) {
  __shared__ __align__(16) unsigned short Ks[64][136];
  __shared__ __align__(16) unsigned short Vt[128][72];
  __shared__ __align__(16) unsigned short Ps[4][32][68];
  int t = threadIdx.x;
  int lane = t & 63, w = t >> 6;
  int id = lane & 15, quad = lane >> 4;
  int blk = blockIdx.x;
  int x = blk & 7, y = blk >> 3;         // y in 0..95
  int tile = y & 31;
  int cid = x*3 + (y >> 5);              // 0..23
  int b = cid & 3;
  int ks = cid >> 2;                     // 0..5
  int ksoff = (ks < 4) ? ks*11 : 44 + (ks - 4)*10;
  int kcnt  = (ks < 4) ? 11 : 10;
  int n0 = tile << 7;
  int r0 = n0 + w*32;

  const unsigned short* Qb = Qg  + (size_t)b*NSP*CH;
  const unsigned short* Kb = Kg  + (size_t)b*NSP*CH;
  const unsigned short* Vb = Vtg + (size_t)b*CH*NSP;

  int kr[4], kc8[4], vr[4], vn[4];
  #pragma unroll
  for (int it = 0; it < 4; ++it) {
    int task = t + it*256;
    kr[it] = task >> 4; kc8[it] = (task & 15) << 3;
    vr[it] = task >> 3; vn[it]  = (task & 7) << 3;
  }

  short8 qf[2][4];
  #pragma unroll
  for (int m = 0; m < 2; ++m)
    #pragma unroll
    for (int kc = 0; kc < 4; ++kc)
      qf[m][kc] = *(const short8*)(Qb + (size_t)(r0 + m*16 + id)*CH + kc*32 + quad*8);

  floatx4 O[2][8];
  #pragma unroll
  for (int m = 0; m < 2; ++m)
    #pragma unroll
    for (int ct = 0; ct < 8; ++ct) O[m][ct] = (floatx4){0.f,0.f,0.f,0.f};
  float lrun[2][4];
  #pragma unroll
  for (int m = 0; m < 2; ++m)
    #pragma unroll
    for (int r = 0; r < 4; ++r) lrun[m][r] = 0.f;

  const float scale = 0.08838834764831845f;

  short8 kreg[4], vreg[4];
  {
    int kbase = ksoff*64;
    #pragma unroll
    for (int it = 0; it < 4; ++it) {
      kreg[it] = *(const short8*)(Kb + (size_t)(kbase + kr[it])*CH + kc8[it]);
      vreg[it] = *(const short8*)(Vb + (size_t)vr[it]*NSP + kbase + vn[it]);
    }
  }

  for (int kt = 0; kt < kcnt; ++kt) {
    __syncthreads();
    #pragma unroll
    for (int it = 0; it < 4; ++it) {
      *(short8*)&Ks[kr[it]][kc8[it]] = kreg[it];
      *(short8*)&Vt[vr[it]][vn[it]]  = vreg[it];
    }
    __syncthreads();
    if (kt < kcnt - 1) {
      int kbase = (ksoff + kt + 1)*64;
      #pragma unroll
      for (int it = 0; it < 4; ++it) {
        kreg[it] = *(const short8*)(Kb + (size_t)(kbase + kr[it])*CH + kc8[it]);
        vreg[it] = *(const short8*)(Vb + (size_t)vr[it]*NSP + kbase + vn[it]);
      }
    }

    floatx4 S[2][4];
    #pragma unroll
    for (int nt = 0; nt < 4; ++nt) {
      floatx4 a0 = (floatx4){0.f,0.f,0.f,0.f};
      floatx4 a1 = (floatx4){0.f,0.f,0.f,0.f};
      #pragma unroll
      for (int kc = 0; kc < 4; ++kc) {
        short8 kf = *(const short8*)&Ks[nt*16 + id][kc*32 + quad*8];
        a0 = __builtin_amdgcn_mfma_f32_16x16x32_bf16(qf[0][kc], kf, a0, 0, 0, 0);
        a1 = __builtin_amdgcn_mfma_f32_16x16x32_bf16(qf[1][kc], kf, a1, 0, 0, 0);
      }
      S[0][nt] = a0; S[1][nt] = a1;
    }
    #pragma unroll
    for (int m = 0; m < 2; ++m) {
      float rs[4] = {0.f,0.f,0.f,0.f};
      #pragma unroll
      for (int nt = 0; nt < 4; ++nt)
        #pragma unroll
        for (int r = 0; r < 4; ++r) {
          float p = __expf(S[m][nt][r] * scale);
          rs[r] += p;
          Ps[w][m*16 + quad*4 + r][nt*16 + id] = f2bu(p);
        }
      #pragma unroll
      for (int off = 1; off <= 8; off <<= 1)
        #pragma unroll
        for (int r = 0; r < 4; ++r) rs[r] += __shfl_xor(rs[r], off, 64);
      #pragma unroll
      for (int r = 0; r < 4; ++r) lrun[m][r] += rs[r];
    }
    #pragma unroll
    for (int nc = 0; nc < 2; ++nc) {
      short8 pf0 = *(const short8*)&Ps[w][id     ][nc*32 + quad*8];
      short8 pf1 = *(const short8*)&Ps[w][16 + id][nc*32 + quad*8];
      #pragma unroll
      for (int ct = 0; ct < 8; ++ct) {
        short8 vf = *(const short8*)&Vt[ct*16 + id][nc*32 + quad*8];
        O[0][ct] = __builtin_amdgcn_mfma_f32_16x16x32_bf16(pf0, vf, O[0][ct], 0, 0, 0);
        O[1][ct] = __builtin_amdgcn_mfma_f32_16x16x32_bf16(pf1, vf, O[1][ct], 0, 0, 0);
      }
    }
  }

  unsigned short* Op = Opart + (size_t)ks*BIG + (size_t)b*NSP*CH;
  #pragma unroll
  for (int m = 0; m < 2; ++m)
    #pragma unroll
    for (int ct = 0; ct < 8; ++ct)
      #pragma unroll
      for (int r = 0; r < 4; ++r) {
        int row = r0 + m*16 + quad*4 + r;
        Op[(size_t)row*CH + ct*16 + id] = f2bu(O[m][ct][r]);
      }
  if (id == 0) {
    float* lp = lpart + (size_t)ks*BATCH*NSP + (size_t)b*NSP;
    #pragma unroll
    for (int m = 0; m < 2; ++m)
      #pragma unroll
      for (int r = 0; r < 4; ++r)
        lp[r0 + m*16 + quad*4 + r] = lrun[m][r];
  }
}

// ---------------- fused combine + output: out = x + (w0*oc + w2*och)^T ----------------
__global__ __launch_bounds__(256) void fuse_kernel(const float* __restrict__ x,
    const unsigned short* __restrict__ Opart, const float* __restrict__ lpart,
    const float* __restrict__ och, const float* __restrict__ wgt,
    float* __restrict__ out) {
  __shared__ float T[128][65];
  __shared__ float linv[64];
  int t = threadIdx.x;
  int b  = blockIdx.x >> 6;
  int n0 = (blockIdx.x & 63) << 6;
  float w0 = wgt[b*3 + 0], w2 = wgt[b*3 + 2];
  if (t < 64) {
    float l = 0.f;
    #pragma unroll
    for (int p = 0; p < FKSPLIT; ++p)
      l += lpart[(size_t)p*BATCH*NSP + b*NSP + n0 + t];
    linv[t] = 1.f / l;
  }
  __syncthreads();
  const float* ochb = och + (size_t)(b*NSP + n0)*CH;
  for (int i = t; i < 8192; i += 256) {
    int n = i >> 7, c = i & 127;
    size_t oidx = (size_t)(b*NSP + n0 + n)*CH + c;
    float o = 0.f;
    #pragma unroll
    for (int p = 0; p < FKSPLIT; ++p) o += b2f(Opart[(size_t)p*BIG + oidx]);
    T[c][n] = w0*o*linv[n] + w2*ochb[(size_t)n*CH + c];
  }
  __syncthreads();
  for (int i = t; i < 8192; i += 256) {
    int c = i >> 6, n = i & 63;
    size_t idx = (size_t)(b*CH + c)*NSP + n0 + n;
    out[idx] = x[idx] + T[c][n];
  }
}

extern "C" void kernel_launch(void* const* d_in, const int* in_sizes, int n_in,
                              void* d_out, int out_size, void* d_ws, size_t ws_size,
                              hipStream_t stream) {
  (void)in_sizes; (void)n_in; (void)out_size; (void)ws_size;
  const float* x     = (const float*)d_in[0];
  const float* ln_g  = (const float*)d_in[1];
  const float* ln_b  = (const float*)d_in[2];
  const float* Wq    = (const float*)d_in[3];
  const float* bq    = (const float*)d_in[4];
  const float* Wk    = (const float*)d_in[5];
  const float* bk    = (const float*)d_in[6];
  const float* Wvc   = (const float*)d_in[7];
  const float* bvc   = (const float*)d_in[8];
  const float* Wvch  = (const float*)d_in[9];
  const float* bvch  = (const float*)d_in[10];
  const float* Wconv = (const float*)d_in[11];
  const float* bconv = (const float*)d_in[12];
  const float* Wg    = (const float*)d_in[13];
  const float* bg    = (const float*)d_in[14];

  float* out = (float*)d_out;
  float* cgf = out + (size_t)BIG;

  char* base = (char*)d_ws;
  float* och  = (float*)(base);                    // 0..8 MB: out_channel (fp32)
  // 8..32 MB: Opart (6 x 4 MB bf16). Overlays: Sp 4 MB @8 (dead after chsoftmax),
  // vcb 4 MB @12 (dead after vtrans) — both precede flash_part.
  unsigned short* Opart = (unsigned short*)(base + 8*(size_t)MB);
  float* Sp             = (float*)(base + 8*(size_t)MB);            // 4 MB
  unsigned short* vcb   = (unsigned short*)(base + 12*(size_t)MB);  // 4 MB
  float* lpart  = (float*)(base + 32*(size_t)MB);                   // 384 KB
  unsigned short* Schb = (unsigned short*)(base + 32*(size_t)MB + 512*1024); // 128 KB
  float* pooled = (float*)(base + 32*(size_t)MB + 768*1024);
  float* wgt    = pooled + BATCH*CH;
  unsigned short* qb   = (unsigned short*)(base + 33*(size_t)MB);   // 4 MB
  unsigned short* kb   = (unsigned short*)(base + 37*(size_t)MB);   // 4 MB
  unsigned short* vct  = (unsigned short*)(base + 41*(size_t)MB);   // 4 MB
  unsigned short* vchb = (unsigned short*)(base + 45*(size_t)MB);   // 4 MB
  unsigned short* xfb  = (unsigned short*)(base + 49*(size_t)MB);   // 4 MB, ends 53 MB

  ln_kernel     <<<256, 256, 0, stream>>>(x, ln_g, ln_b, xfb);
  pooled_kernel <<<512, 256, 0, stream>>>(x, pooled);
  gate_kernel   <<<1,   64,  0, stream>>>(pooled, Wg, bg, wgt);
  conv_kernel   <<<1024, 256, 0, stream>>>(xfb, Wconv, bconv, cgf);
  proj_mfma_kernel<<<dim3(128,4), 256, 0, stream>>>(xfb, Wq, Wk, Wvc, Wvch,
                                                    bq, bk, bvc, bvch,
                                                    qb, kb, vcb, vchb);
  vtrans_kernel <<<256, 256, 0, stream>>>(vcb, vct);
  chscore_kernel<<<dim3(KCHUNKS, BATCH), 256, 0, stream>>>(qb, kb, Sp);
  chsoftmax_kernel<<<512, 64, 0, stream>>>(Sp, Schb);
  chout_mfma_kernel<<<128, 256, 0, stream>>>(vchb, Schb, och);
  flash_part_kernel<<<768, 256, 0, stream>>>(qb, kb, vct, Opart, lpart);
  fuse_kernel   <<<256, 256, 0, stream>>>(x, Opart, lpart, och, wgt, out);
}

// Round 11
// 227.299 us; speedup vs baseline: 1.0111x; 1.0111x over previous
//
#include <hip/hip_runtime.h>
#include <math.h>

#define CH   128
#define NSP  4096
#define BATCH 4
#define BIG  (BATCH*NSP*CH)   // 2,097,152 elements per (B,N,C) buffer
#define KCHUNKS 64            // split-K chunks for chscore (64 n-rows each)
#define FKSPLIT 4             // split-K for flash (16 x 64-row K-tiles each)
#define MB (1024*1024)

typedef short short8 __attribute__((ext_vector_type(8)));
typedef float floatx4 __attribute__((ext_vector_type(4)));

#define QSCALE 0.08838834764831845f   // 1/sqrt(128), folded into q at projection

__device__ __forceinline__ unsigned short f2bu(float f) {
  union { float f; unsigned u; } v; v.f = f;
  unsigned r = v.u + 0x7fffu + ((v.u >> 16) & 1u);
  return (unsigned short)(r >> 16);
}
__device__ __forceinline__ float b2f(unsigned short h) {
  union { unsigned u; float f; } v; v.u = ((unsigned)h) << 16;
  return v.f;
}

// ---------------- LayerNorm over channels → xfb bf16 ----------------
__global__ __launch_bounds__(256) void ln_kernel(const float* __restrict__ x,
    const float* __restrict__ g, const float* __restrict__ bta,
    unsigned short* __restrict__ xfb) {
  __shared__ float tile[128][65];
  __shared__ float pS[4][64];
  __shared__ float pQ[4][64];
  __shared__ float mu_s[64], rs_s[64];
  int t = threadIdx.x;
  int b  = blockIdx.x >> 6;
  int n0 = (blockIdx.x & 63) << 6;
  for (int i = t; i < 8192; i += 256) {
    int c = i >> 6, n = i & 63;
    tile[c][n] = x[(size_t)(b*CH + c)*NSP + n0 + n];
  }
  __syncthreads();
  {
    int n = t & 63, part = t >> 6;
    float s = 0.f, qq = 0.f;
    for (int c = part; c < 128; c += 4) { float v = tile[c][n]; s += v; qq += v*v; }
    pS[part][n] = s; pQ[part][n] = qq;
  }
  __syncthreads();
  if (t < 64) {
    float s = pS[0][t] + pS[1][t] + pS[2][t] + pS[3][t];
    float qq = pQ[0][t] + pQ[1][t] + pQ[2][t] + pQ[3][t];
    float mu = s * (1.f/128.f);
    float var = qq * (1.f/128.f) - mu*mu;
    mu_s[t] = mu;
    rs_s[t] = rsqrtf(var + 1e-5f);
  }
  __syncthreads();
  for (int i = t; i < 8192; i += 256) {
    int n = i >> 7, c = i & 127;
    float v = (tile[c][n] - mu_s[n]) * rs_s[n] * g[c] + bta[c];
    xfb[(size_t)(b*NSP + n0 + n)*CH + c] = f2bu(v);
  }
}

// ---------------- pooled = mean over spatial → (B,C) ----------------
__global__ __launch_bounds__(256) void pooled_kernel(const float* __restrict__ x,
                                                     float* __restrict__ pooled) {
  int bc = blockIdx.x; int t = threadIdx.x;
  const float4* p = (const float4*)(x + (size_t)bc*NSP);
  float s = 0.f;
  for (int i = t; i < 1024; i += 256) { float4 v = p[i]; s += v.x+v.y+v.z+v.w; }
  for (int off = 32; off; off >>= 1) s += __shfl_xor(s, off, 64);
  __shared__ float red[4];
  if ((t & 63) == 0) red[t >> 6] = s;
  __syncthreads();
  if (t == 0) pooled[bc] = (red[0]+red[1]+red[2]+red[3]) * (1.f/4096.f);
}

// ---------------- Conv3d C->2, k=3, SAME — wave-cluster reduction ----------------
__global__ __launch_bounds__(256) void conv_kernel(const unsigned short* __restrict__ xfb,
    const float* __restrict__ Wc, const float* __restrict__ bc_, float* __restrict__ cgf) {
  __shared__ float Wl[27*256];                 // [tap][o][c] = 27.6 KB
  int t = threadIdx.x;
  for (int i = t; i < 6912; i += 256) {
    int tap = i >> 8;
    int rem = i & 255;
    int o = rem >> 7, c = rem & 127;
    Wl[i] = Wc[o*3456 + c*27 + tap];
  }
  __syncthreads();
  int cg = t & 15, spl = t >> 4;
  int sp = blockIdx.x*16 + spl;                // 0..16383
  int b = sp >> 12, n = sp & 4095;
  int z = n >> 8, y = (n >> 4) & 15, xw = n & 15;
  const unsigned short* xb = xfb + (size_t)b*NSP*CH + cg*8;
  float a0 = 0.f, a1 = 0.f;
  for (int kd = 0; kd < 3; ++kd) {
    int zz = z + kd - 1; if ((unsigned)zz >= 16u) continue;
    for (int kh = 0; kh < 3; ++kh) {
      int yy = y + kh - 1; if ((unsigned)yy >= 16u) continue;
      #pragma unroll
      for (int kw = 0; kw < 3; ++kw) {
        int xx = xw + kw - 1; if ((unsigned)xx >= 16u) continue;
        int nn = (zz << 8) + (yy << 4) + xx;
        short8 xv = *(const short8*)(xb + (size_t)nn*CH);
        int tap = (kd*3 + kh)*3 + kw;
        const float* wbase = &Wl[tap*256 + cg*8];
        float4 w00 = *(const float4*)(wbase);
        float4 w01 = *(const float4*)(wbase + 4);
        float4 w10 = *(const float4*)(wbase + 128);
        float4 w11 = *(const float4*)(wbase + 132);
        float x0 = b2f((unsigned short)xv[0]), x1 = b2f((unsigned short)xv[1]);
        float x2 = b2f((unsigned short)xv[2]), x3 = b2f((unsigned short)xv[3]);
        float x4 = b2f((unsigned short)xv[4]), x5 = b2f((unsigned short)xv[5]);
        float x6 = b2f((unsigned short)xv[6]), x7 = b2f((unsigned short)xv[7]);
        a0 += x0*w00.x + x1*w00.y + x2*w00.z + x3*w00.w
            + x4*w01.x + x5*w01.y + x6*w01.z + x7*w01.w;
        a1 += x0*w10.x + x1*w10.y + x2*w10.z + x3*w10.w
            + x4*w11.x + x5*w11.y + x6*w11.z + x7*w11.w;
      }
    }
  }
  #pragma unroll
  for (int off = 1; off <= 8; off <<= 1) {
    a0 += __shfl_xor(a0, off, 64);
    a1 += __shfl_xor(a1, off, 64);
  }
  if (cg == 0) {
    cgf[b*8192 + n]        = a0 + bc_[0];
    cgf[b*8192 + 4096 + n] = a1 + bc_[1];
  }
}

// ---------------- MFMA projection: Y = X W^T + b (fp32 W converted in staging) ----------------
// pj==0 (q) output is pre-scaled by QSCALE (compensated in chsoftmax).
__global__ __launch_bounds__(256) void proj_mfma_kernel(
    const unsigned short* __restrict__ xfb,
    const float* __restrict__ Wq, const float* __restrict__ Wk,
    const float* __restrict__ Wvc, const float* __restrict__ Wvch,
    const float* __restrict__ bq, const float* __restrict__ bk,
    const float* __restrict__ bvc, const float* __restrict__ bvch,
    unsigned short* __restrict__ q, unsigned short* __restrict__ k,
    unsigned short* __restrict__ vc, unsigned short* __restrict__ vch) {
  __shared__ __align__(16) unsigned short Ws[128][136];
  int t = threadIdx.x;
  int lane = t & 63, w = t >> 6;
  int id = lane & 15, quad = lane >> 4;
  int pj = blockIdx.y;
  int r0 = blockIdx.x*128 + w*32;

  const float* Wp = (pj == 0) ? Wq : (pj == 1) ? Wk : (pj == 2) ? Wvc : Wvch;
  for (int i = t; i < 2048; i += 256) {
    int rr = i >> 4, c8 = (i & 15) << 3;
    const float* src = Wp + rr*CH + c8;
    short8 pk;
    #pragma unroll
    for (int j = 0; j < 8; ++j) pk[j] = (short)f2bu(src[j]);
    *(short8*)&Ws[rr][c8] = pk;
  }
  short8 af[2][4];
  #pragma unroll
  for (int m = 0; m < 2; ++m)
    #pragma unroll
    for (int kc = 0; kc < 4; ++kc)
      af[m][kc] = *(const short8*)(xfb + (size_t)(r0 + m*16 + id)*CH + kc*32 + quad*8);
  __syncthreads();

  floatx4 acc[2][8];
  #pragma unroll
  for (int m = 0; m < 2; ++m)
    #pragma unroll
    for (int nt = 0; nt < 8; ++nt) acc[m][nt] = (floatx4){0.f,0.f,0.f,0.f};
  #pragma unroll
  for (int nt = 0; nt < 8; ++nt)
    #pragma unroll
    for (int kc = 0; kc < 4; ++kc) {
      short8 bf = *(const short8*)&Ws[nt*16 + id][kc*32 + quad*8];
      acc[0][nt] = __builtin_amdgcn_mfma_f32_16x16x32_bf16(af[0][kc], bf, acc[0][nt], 0, 0, 0);
      acc[1][nt] = __builtin_amdgcn_mfma_f32_16x16x32_bf16(af[1][kc], bf, acc[1][nt], 0, 0, 0);
    }

  const float* bias = (pj == 0) ? bq : (pj == 1) ? bk : (pj == 2) ? bvc : bvch;
  unsigned short* Y = (pj == 0) ? q : (pj == 1) ? k : (pj == 2) ? vc : vch;
  float osc = (pj == 0) ? QSCALE : 1.f;
  #pragma unroll
  for (int nt = 0; nt < 8; ++nt) {
    float bsv = bias[nt*16 + id];
    #pragma unroll
    for (int m = 0; m < 2; ++m)
      #pragma unroll
      for (int r = 0; r < 4; ++r) {
        int row = r0 + m*16 + quad*4 + r;
        Y[(size_t)row*CH + nt*16 + id] = f2bu((acc[m][nt][r] + bsv) * osc);
      }
  }
}

// ---------------- transpose vc (B,N,C) -> vct (B,C,N), bf16 ----------------
__global__ __launch_bounds__(256) void vtrans_kernel(const unsigned short* __restrict__ vc,
                                                     unsigned short* __restrict__ vct) {
  __shared__ unsigned short T[128][72];   // [c][n], 64 n per tile
  int t = threadIdx.x;
  int b = blockIdx.x >> 6, n0 = (blockIdx.x & 63) << 6;
  for (int i = t; i < 1024; i += 256) {
    int n = i >> 4, c0 = (i & 15) << 3;
    short8 v = *(const short8*)&vc[(size_t)(b*NSP + n0 + n)*CH + c0];
    #pragma unroll
    for (int j = 0; j < 8; ++j) T[c0+j][n] = (unsigned short)v[j];
  }
  __syncthreads();
  for (int i = t; i < 1024; i += 256) {
    int c = i >> 3, k8 = (i & 7) << 3;
    *(short8*)&vct[((size_t)b*CH + c)*NSP + n0 + k8] = *(short8*)&T[c][k8];
  }
}

// ---------------- channel scores: split-K MFMA, 64 rows/chunk. Sp[p][b][c][d] ----------------
__global__ __launch_bounds__(256) void chscore_kernel(const unsigned short* __restrict__ q,
    const unsigned short* __restrict__ k, float* __restrict__ Sp) {
  __shared__ unsigned short Qt[128][72];
  __shared__ unsigned short Kt[128][72];
  int t = threadIdx.x;
  int lane = t & 63, w = t >> 6;
  int id = lane & 15, quad = lane >> 4;
  int p = blockIdx.x;                      // 0..63, 64 n-rows each
  int b = blockIdx.y;
  const unsigned short* qb = q + (size_t)b*NSP*CH;
  const unsigned short* kb = k + (size_t)b*NSP*CH;
  int nbase = p*64;

  #pragma unroll
  for (int it = 0; it < 4; ++it) {
    int task = t + it*256;
    int c = task & 127, r0 = (task >> 7) << 3;
    short8 vq, vk;
    #pragma unroll
    for (int j = 0; j < 8; ++j) {
      size_t off = (size_t)(nbase + r0 + j)*CH + c;
      vq[j] = (short)qb[off];
      vk[j] = (short)kb[off];
    }
    *(short8*)&Qt[c][r0] = vq;
    *(short8*)&Kt[c][r0] = vk;
  }
  __syncthreads();

  floatx4 acc[2][8];
  #pragma unroll
  for (int mt = 0; mt < 2; ++mt)
    #pragma unroll
    for (int nt = 0; nt < 8; ++nt) acc[mt][nt] = (floatx4){0.f,0.f,0.f,0.f};
  #pragma unroll
  for (int kc = 0; kc < 2; ++kc) {
    short8 af0 = *(const short8*)&Qt[w*32 + id     ][kc*32 + quad*8];
    short8 af1 = *(const short8*)&Qt[w*32 + 16 + id][kc*32 + quad*8];
    #pragma unroll
    for (int nt = 0; nt < 8; ++nt) {
      short8 bf = *(const short8*)&Kt[nt*16 + id][kc*32 + quad*8];
      acc[0][nt] = __builtin_amdgcn_mfma_f32_16x16x32_bf16(af0, bf, acc[0][nt], 0, 0, 0);
      acc[1][nt] = __builtin_amdgcn_mfma_f32_16x16x32_bf16(af1, bf, acc[1][nt], 0, 0, 0);
    }
  }
  float* outp = Sp + ((size_t)(p*BATCH + b) << 14);
  #pragma unroll
  for (int mt = 0; mt < 2; ++mt)
    #pragma unroll
    for (int nt = 0; nt < 8; ++nt)
      #pragma unroll
      for (int r = 0; r < 4; ++r) {
        int c = w*32 + mt*16 + quad*4 + r;
        int d = nt*16 + id;
        outp[c*CH + d] = acc[mt][nt][r];
      }
}

// reduce split-K partials + softmax; q was pre-scaled by QSCALE so scale = 1/(64*QSCALE)
__global__ __launch_bounds__(64) void chsoftmax_kernel(const float* __restrict__ Sp,
                                                       unsigned short* __restrict__ Sb) {
  int row = blockIdx.x;
  int b = row >> 7, c = row & 127;
  int t = threadIdx.x;
  float s0 = 0.f, s1 = 0.f;
  #pragma unroll 4
  for (int p = 0; p < KCHUNKS; ++p) {
    const float* r = Sp + (((size_t)(p*BATCH + b) << 7) + c)*CH;
    s0 += r[t]; s1 += r[t+64];
  }
  const float sc = (1.f/64.f) / QSCALE;
  s0 *= sc; s1 *= sc;
  float m = fmaxf(s0, s1);
  for (int off = 32; off; off >>= 1) m = fmaxf(m, __shfl_xor(m, off, 64));
  float p0 = __expf(s0 - m), p1 = __expf(s1 - m);
  float s = p0 + p1;
  for (int off = 32; off; off >>= 1) s += __shfl_xor(s, off, 64);
  float inv = 1.f/s;
  unsigned short* r = Sb + (size_t)row*CH;
  r[t]    = f2bu(p0*inv);
  r[t+64] = f2bu(p1*inv);
}

// ---------------- channel-attention apply ----------------
__global__ __launch_bounds__(256) void chout_mfma_kernel(
    const unsigned short* __restrict__ vchb, const unsigned short* __restrict__ Sb,
    float* __restrict__ och) {
  __shared__ __align__(16) unsigned short As[128][136];
  int t = threadIdx.x;
  int lane = t & 63, w = t >> 6;
  int id = lane & 15, quad = lane >> 4;
  int b = blockIdx.x >> 5;
  int r0 = blockIdx.x*128 + w*32;

  const unsigned short* Sp = Sb + ((size_t)b << 14);
  for (int i = t; i < 2048; i += 256) {
    int rr = i >> 4, c8 = (i & 15) << 3;
    *(short8*)&As[rr][c8] = *(const short8*)(Sp + rr*CH + c8);
  }
  short8 af[2][4];
  #pragma unroll
  for (int m = 0; m < 2; ++m)
    #pragma unroll
    for (int kc = 0; kc < 4; ++kc)
      af[m][kc] = *(const short8*)(vchb + (size_t)(r0 + m*16 + id)*CH + kc*32 + quad*8);
  __syncthreads();

  floatx4 acc[2][8];
  #pragma unroll
  for (int m = 0; m < 2; ++m)
    #pragma unroll
    for (int nt = 0; nt < 8; ++nt) acc[m][nt] = (floatx4){0.f,0.f,0.f,0.f};
  #pragma unroll
  for (int nt = 0; nt < 8; ++nt)
    #pragma unroll
    for (int kc = 0; kc < 4; ++kc) {
      short8 bf = *(const short8*)&As[nt*16 + id][kc*32 + quad*8];
      acc[0][nt] = __builtin_amdgcn_mfma_f32_16x16x32_bf16(af[0][kc], bf, acc[0][nt], 0, 0, 0);
      acc[1][nt] = __builtin_amdgcn_mfma_f32_16x16x32_bf16(af[1][kc], bf, acc[1][nt], 0, 0, 0);
    }
  #pragma unroll
  for (int nt = 0; nt < 8; ++nt)
    #pragma unroll
    for (int m = 0; m < 2; ++m)
      #pragma unroll
      for (int r = 0; r < 4; ++r) {
        int row = r0 + m*16 + quad*4 + r;
        och[(size_t)row*CH + nt*16 + id] = acc[m][nt][r];
      }
}

// ---------------- flash partial: split-K x4, register-pipelined (R9 config) ----------------
// l row-sums computed by MFMA with an all-ones B fragment (D[m][n] = sum_k P[m][k]),
// accumulated in AGPRs across all iterations — replaces per-iter shuffle reductions.
__global__ __launch_bounds__(256) void flash_part_kernel(
    const unsigned short* __restrict__ Qg, const unsigned short* __restrict__ Kg,
    const unsigned short* __restrict__ Vtg,
    unsigned short* __restrict__ Opart, float* __restrict__ lpart) {
  __shared__ __align__(16) unsigned short Ks[64][136];
  __shared__ __align__(16) unsigned short Vt[128][72];
  __shared__ __align__(16) unsigned short Ps[4][32][68];
  int t = threadIdx.x;
  int lane = t & 63, w = t >> 6;
  int id = lane & 15, quad = lane >> 4;
  int blk = blockIdx.x;
  int x = blk & 7, y = blk >> 3;
  int tile = y & 31;
  int b = x >> 1;
  int ks = (x & 1) + ((y >> 5) << 1);    // 0..3
  int n0 = tile << 7;
  int r0 = n0 + w*32;

  const unsigned short* Qb = Qg  + (size_t)b*NSP*CH;
  const unsigned short* Kb = Kg  + (size_t)b*NSP*CH;
  const unsigned short* Vb = Vtg + (size_t)b*CH*NSP;

  int kr[4], kc8[4], vr[4], vn[4];
  #pragma unroll
  for (int it = 0; it < 4; ++it) {
    int task = t + it*256;
    kr[it] = task >> 4; kc8[it] = (task & 15) << 3;
    vr[it] = task >> 3; vn[it]  = (task & 7) << 3;
  }

  short8 qf[2][4];
  #pragma unroll
  for (int m = 0; m < 2; ++m)
    #pragma unroll
    for (int kc = 0; kc < 4; ++kc)
      qf[m][kc] = *(const short8*)(Qb + (size_t)(r0 + m*16 + id)*CH + kc*32 + quad*8);

  floatx4 O[2][8];
  #pragma unroll
  for (int m = 0; m < 2; ++m)
    #pragma unroll
    for (int ct = 0; ct < 8; ++ct) O[m][ct] = (floatx4){0.f,0.f,0.f,0.f};
  floatx4 lacc0 = (floatx4){0.f,0.f,0.f,0.f};
  floatx4 lacc1 = (floatx4){0.f,0.f,0.f,0.f};
  short8 ones;
  #pragma unroll
  for (int j = 0; j < 8; ++j) ones[j] = (short)0x3F80;   // bf16 1.0

  short8 kreg[4], vreg[4];
  {
    int kbase = ks*1024;
    #pragma unroll
    for (int it = 0; it < 4; ++it) {
      kreg[it] = *(const short8*)(Kb + (size_t)(kbase + kr[it])*CH + kc8[it]);
      vreg[it] = *(const short8*)(Vb + (size_t)vr[it]*NSP + kbase + vn[it]);
    }
  }

  for (int kt = 0; kt < 16; ++kt) {
    __syncthreads();
    #pragma unroll
    for (int it = 0; it < 4; ++it) {
      *(short8*)&Ks[kr[it]][kc8[it]] = kreg[it];
      *(short8*)&Vt[vr[it]][vn[it]]  = vreg[it];
    }
    __syncthreads();
    if (kt < 15) {
      int kbase = ks*1024 + (kt+1)*64;
      #pragma unroll
      for (int it = 0; it < 4; ++it) {
        kreg[it] = *(const short8*)(Kb + (size_t)(kbase + kr[it])*CH + kc8[it]);
        vreg[it] = *(const short8*)(Vb + (size_t)vr[it]*NSP + kbase + vn[it]);
      }
    }

    floatx4 S[2][4];
    #pragma unroll
    for (int nt = 0; nt < 4; ++nt) {
      floatx4 a0 = (floatx4){0.f,0.f,0.f,0.f};
      floatx4 a1 = (floatx4){0.f,0.f,0.f,0.f};
      #pragma unroll
      for (int kc = 0; kc < 4; ++kc) {
        short8 kf = *(const short8*)&Ks[nt*16 + id][kc*32 + quad*8];
        a0 = __builtin_amdgcn_mfma_f32_16x16x32_bf16(qf[0][kc], kf, a0, 0, 0, 0);
        a1 = __builtin_amdgcn_mfma_f32_16x16x32_bf16(qf[1][kc], kf, a1, 0, 0, 0);
      }
      S[0][nt] = a0; S[1][nt] = a1;
    }
    // p = exp(s) (q pre-scaled); store P to LDS; l comes from MFMA below
    #pragma unroll
    for (int m = 0; m < 2; ++m)
      #pragma unroll
      for (int nt = 0; nt < 4; ++nt)
        #pragma unroll
        for (int r = 0; r < 4; ++r)
          Ps[w][m*16 + quad*4 + r][nt*16 + id] = f2bu(__expf(S[m][nt][r]));

    #pragma unroll
    for (int nc = 0; nc < 2; ++nc) {
      short8 pf0 = *(const short8*)&Ps[w][id     ][nc*32 + quad*8];
      short8 pf1 = *(const short8*)&Ps[w][16 + id][nc*32 + quad*8];
      lacc0 = __builtin_amdgcn_mfma_f32_16x16x32_bf16(pf0, ones, lacc0, 0, 0, 0);
      lacc1 = __builtin_amdgcn_mfma_f32_16x16x32_bf16(pf1, ones, lacc1, 0, 0, 0);
      #pragma unroll
      for (int ct = 0; ct < 8; ++ct) {
        short8 vf = *(const short8*)&Vt[ct*16 + id][nc*32 + quad*8];
        O[0][ct] = __builtin_amdgcn_mfma_f32_16x16x32_bf16(pf0, vf, O[0][ct], 0, 0, 0);
        O[1][ct] = __builtin_amdgcn_mfma_f32_16x16x32_bf16(pf1, vf, O[1][ct], 0, 0, 0);
      }
    }
  }

  unsigned short* Op = Opart + (size_t)ks*BIG + (size_t)b*NSP*CH;
  #pragma unroll
  for (int m = 0; m < 2; ++m)
    #pragma unroll
    for (int ct = 0; ct < 8; ++ct)
      #pragma unroll
      for (int r = 0; r < 4; ++r) {
        int row = r0 + m*16 + quad*4 + r;
        Op[(size_t)row*CH + ct*16 + id] = f2bu(O[m][ct][r]);
      }
  if (id == 0) {
    float* lp = lpart + (size_t)ks*BATCH*NSP + (size_t)b*NSP;
    #pragma unroll
    for (int r = 0; r < 4; ++r) {
      lp[r0 + quad*4 + r]      = lacc0[r];
      lp[r0 + 16 + quad*4 + r] = lacc1[r];
    }
  }
}

// ---------------- fused combine + gate + output: out = x + (w0*oc + w2*och)^T ----------------
__global__ __launch_bounds__(256) void fuse_kernel(const float* __restrict__ x,
    const unsigned short* __restrict__ Opart, const float* __restrict__ lpart,
    const float* __restrict__ och, const float* __restrict__ pooled,
    const float* __restrict__ Wg, const float* __restrict__ bg,
    float* __restrict__ out) {
  __shared__ float T[128][65];
  __shared__ float linv[64];
  __shared__ float wsh[2];
  int t = threadIdx.x;
  int b  = blockIdx.x >> 6;
  int n0 = (blockIdx.x & 63) << 6;
  if (t < 64) {
    float l = 0.f;
    #pragma unroll
    for (int p = 0; p < FKSPLIT; ++p)
      l += lpart[(size_t)p*BATCH*NSP + b*NSP + n0 + t];
    linv[t] = 1.f / l;
    // gate: 3 dots of pooled[b] with Wg rows, lane-parallel + shuffle reduce
    float p0 = pooled[b*CH + t], p1 = pooled[b*CH + 64 + t];
    float d0 = p0*Wg[t]       + p1*Wg[64 + t];
    float d1 = p0*Wg[128 + t] + p1*Wg[192 + t];
    float d2 = p0*Wg[256 + t] + p1*Wg[320 + t];
    #pragma unroll
    for (int off = 32; off; off >>= 1) {
      d0 += __shfl_xor(d0, off, 64);
      d1 += __shfl_xor(d1, off, 64);
      d2 += __shfl_xor(d2, off, 64);
    }
    if (t == 0) {
      d0 += bg[0]; d1 += bg[1]; d2 += bg[2];
      float m = fmaxf(d0, fmaxf(d1, d2));
      float e0 = __expf(d0 - m), e1 = __expf(d1 - m), e2 = __expf(d2 - m);
      float inv = 1.f/(e0 + e1 + e2);
      wsh[0] = e0*inv;     // w0
      wsh[1] = e2*inv;     // w2
    }
  }
  __syncthreads();
  float w0 = wsh[0], w2 = wsh[1];
  const float* ochb = och + (size_t)(b*NSP + n0)*CH;
  for (int i = t; i < 8192; i += 256) {
    int n = i >> 7, c = i & 127;
    size_t oidx = (size_t)(b*NSP + n0 + n)*CH + c;
    float o = 0.f;
    #pragma unroll
    for (int p = 0; p < FKSPLIT; ++p) o += b2f(Opart[(size_t)p*BIG + oidx]);
    T[c][n] = w0*o*linv[n] + w2*ochb[(size_t)n*CH + c];
  }
  __syncthreads();
  for (int i = t; i < 8192; i += 256) {
    int c = i >> 6, n = i & 63;
    size_t idx = (size_t)(b*CH + c)*NSP + n0 + n;
    out[idx] = x[idx] + T[c][n];
  }
}

extern "C" void kernel_launch(void* const* d_in, const int* in_sizes, int n_in,
                              void* d_out, int out_size, void* d_ws, size_t ws_size,
                              hipStream_t stream) {
  (void)in_sizes; (void)n_in; (void)out_size; (void)ws_size;
  const float* x     = (const float*)d_in[0];
  const float* ln_g  = (const float*)d_in[1];
  const float* ln_b  = (const float*)d_in[2];
  const float* Wq    = (const float*)d_in[3];
  const float* bq    = (const float*)d_in[4];
  const float* Wk    = (const float*)d_in[5];
  const float* bk    = (const float*)d_in[6];
  const float* Wvc   = (const float*)d_in[7];
  const float* bvc   = (const float*)d_in[8];
  const float* Wvch  = (const float*)d_in[9];
  const float* bvch  = (const float*)d_in[10];
  const float* Wconv = (const float*)d_in[11];
  const float* bconv = (const float*)d_in[12];
  const float* Wg    = (const float*)d_in[13];
  const float* bg    = (const float*)d_in[14];

  float* out = (float*)d_out;
  float* cgf = out + (size_t)BIG;

  char* base = (char*)d_ws;
  float* och  = (float*)(base);                    // 0..8 MB: out_channel (fp32)
  // 8..24 MB: Opart (4 x 4 MB bf16), overlaying Sp (16 MB @8, dead after chsoftmax).
  // vcb @24 is dead after vtrans.
  unsigned short* Opart = (unsigned short*)(base + 8*(size_t)MB);
  float* Sp             = (float*)(base + 8*(size_t)MB);            // 16 MB
  unsigned short* vcb   = (unsigned short*)(base + 24*(size_t)MB);  // 4 MB
  float* lpart  = (float*)(base + 32*(size_t)MB);                   // 256 KB
  unsigned short* Schb = (unsigned short*)(base + 32*(size_t)MB + 512*1024); // 128 KB
  float* pooled = (float*)(base + 32*(size_t)MB + 768*1024);
  unsigned short* qb   = (unsigned short*)(base + 33*(size_t)MB);   // 4 MB
  unsigned short* kb   = (unsigned short*)(base + 37*(size_t)MB);   // 4 MB
  unsigned short* vct  = (unsigned short*)(base + 41*(size_t)MB);   // 4 MB
  unsigned short* vchb = (unsigned short*)(base + 45*(size_t)MB);   // 4 MB
  unsigned short* xfb  = (unsigned short*)(base + 49*(size_t)MB);   // 4 MB, ends 53 MB

  ln_kernel     <<<256, 256, 0, stream>>>(x, ln_g, ln_b, xfb);
  pooled_kernel <<<512, 256, 0, stream>>>(x, pooled);
  conv_kernel   <<<1024, 256, 0, stream>>>(xfb, Wconv, bconv, cgf);
  proj_mfma_kernel<<<dim3(128,4), 256, 0, stream>>>(xfb, Wq, Wk, Wvc, Wvch,
                                                    bq, bk, bvc, bvch,
                                                    qb, kb, vcb, vchb);
  vtrans_kernel <<<256, 256, 0, stream>>>(vcb, vct);
  chscore_kernel<<<dim3(KCHUNKS, BATCH), 256, 0, stream>>>(qb, kb, Sp);
  chsoftmax_kernel<<<512, 64, 0, stream>>>(Sp, Schb);
  chout_mfma_kernel<<<128, 256, 0, stream>>>(vchb, Schb, och);
  flash_part_kernel<<<512, 256, 0, stream>>>(qb, kb, vct, Opart, lpart);
  fuse_kernel   <<<256, 256, 0, stream>>>(x, Opart, lpart, och, pooled, Wg, bg, out);
}

// Round 12
// 216.795 us; speedup vs baseline: 1.0601x; 1.0484x over previous
//
#include <hip/hip_runtime.h>
#include <math.h>

#define CH   128
#define NSP  4096
#define BATCH 4
#define BIG  (BATCH*NSP*CH)   // 2,097,152 elements per (B,N,C) buffer
#define KCHUNKS 64            // split-K chunks for chscore (64 n-rows each)
#define FKSPLIT 4             // split-K for flash (16 x 64-row K-tiles each)
#define MB (1024*1024)

typedef short short8 __attribute__((ext_vector_type(8)));
typedef float floatx4 __attribute__((ext_vector_type(4)));

#define QSCALE 0.08838834764831845f   // 1/sqrt(128), folded into q at projection

__device__ __forceinline__ unsigned short f2bu(float f) {
  union { float f; unsigned u; } v; v.f = f;
  unsigned r = v.u + 0x7fffu + ((v.u >> 16) & 1u);
  return (unsigned short)(r >> 16);
}
__device__ __forceinline__ float b2f(unsigned short h) {
  union { unsigned u; float f; } v; v.u = ((unsigned)h) << 16;
  return v.f;
}

// ---------------- LayerNorm over channels → xfb bf16 ----------------
__global__ __launch_bounds__(256) void ln_kernel(const float* __restrict__ x,
    const float* __restrict__ g, const float* __restrict__ bta,
    unsigned short* __restrict__ xfb) {
  __shared__ float tile[128][65];
  __shared__ float pS[4][64];
  __shared__ float pQ[4][64];
  __shared__ float mu_s[64], rs_s[64];
  int t = threadIdx.x;
  int b  = blockIdx.x >> 6;
  int n0 = (blockIdx.x & 63) << 6;
  for (int i = t; i < 8192; i += 256) {
    int c = i >> 6, n = i & 63;
    tile[c][n] = x[(size_t)(b*CH + c)*NSP + n0 + n];
  }
  __syncthreads();
  {
    int n = t & 63, part = t >> 6;
    float s = 0.f, qq = 0.f;
    for (int c = part; c < 128; c += 4) { float v = tile[c][n]; s += v; qq += v*v; }
    pS[part][n] = s; pQ[part][n] = qq;
  }
  __syncthreads();
  if (t < 64) {
    float s = pS[0][t] + pS[1][t] + pS[2][t] + pS[3][t];
    float qq = pQ[0][t] + pQ[1][t] + pQ[2][t] + pQ[3][t];
    float mu = s * (1.f/128.f);
    float var = qq * (1.f/128.f) - mu*mu;
    mu_s[t] = mu;
    rs_s[t] = rsqrtf(var + 1e-5f);
  }
  __syncthreads();
  for (int i = t; i < 8192; i += 256) {
    int n = i >> 7, c = i & 127;
    float v = (tile[c][n] - mu_s[n]) * rs_s[n] * g[c] + bta[c];
    xfb[(size_t)(b*NSP + n0 + n)*CH + c] = f2bu(v);
  }
}

// ---------------- pooled = mean over spatial → (B,C) ----------------
__global__ __launch_bounds__(256) void pooled_kernel(const float* __restrict__ x,
                                                     float* __restrict__ pooled) {
  int bc = blockIdx.x; int t = threadIdx.x;
  const float4* p = (const float4*)(x + (size_t)bc*NSP);
  float s = 0.f;
  for (int i = t; i < 1024; i += 256) { float4 v = p[i]; s += v.x+v.y+v.z+v.w; }
  for (int off = 32; off; off >>= 1) s += __shfl_xor(s, off, 64);
  __shared__ float red[4];
  if ((t & 63) == 0) red[t >> 6] = s;
  __syncthreads();
  if (t == 0) pooled[bc] = (red[0]+red[1]+red[2]+red[3]) * (1.f/4096.f);
}

// ---------------- Conv3d C->2, k=3, SAME — wave-cluster reduction ----------------
__global__ __launch_bounds__(256) void conv_kernel(const unsigned short* __restrict__ xfb,
    const float* __restrict__ Wc, const float* __restrict__ bc_, float* __restrict__ cgf) {
  __shared__ float Wl[27*256];                 // [tap][o][c] = 27.6 KB
  int t = threadIdx.x;
  for (int i = t; i < 6912; i += 256) {
    int tap = i >> 8;
    int rem = i & 255;
    int o = rem >> 7, c = rem & 127;
    Wl[i] = Wc[o*3456 + c*27 + tap];
  }
  __syncthreads();
  int cg = t & 15, spl = t >> 4;
  int sp = blockIdx.x*16 + spl;                // 0..16383
  int b = sp >> 12, n = sp & 4095;
  int z = n >> 8, y = (n >> 4) & 15, xw = n & 15;
  const unsigned short* xb = xfb + (size_t)b*NSP*CH + cg*8;
  float a0 = 0.f, a1 = 0.f;
  for (int kd = 0; kd < 3; ++kd) {
    int zz = z + kd - 1; if ((unsigned)zz >= 16u) continue;
    for (int kh = 0; kh < 3; ++kh) {
      int yy = y + kh - 1; if ((unsigned)yy >= 16u) continue;
      #pragma unroll
      for (int kw = 0; kw < 3; ++kw) {
        int xx = xw + kw - 1; if ((unsigned)xx >= 16u) continue;
        int nn = (zz << 8) + (yy << 4) + xx;
        short8 xv = *(const short8*)(xb + (size_t)nn*CH);
        int tap = (kd*3 + kh)*3 + kw;
        const float* wbase = &Wl[tap*256 + cg*8];
        float4 w00 = *(const float4*)(wbase);
        float4 w01 = *(const float4*)(wbase + 4);
        float4 w10 = *(const float4*)(wbase + 128);
        float4 w11 = *(const float4*)(wbase + 132);
        float x0 = b2f((unsigned short)xv[0]), x1 = b2f((unsigned short)xv[1]);
        float x2 = b2f((unsigned short)xv[2]), x3 = b2f((unsigned short)xv[3]);
        float x4 = b2f((unsigned short)xv[4]), x5 = b2f((unsigned short)xv[5]);
        float x6 = b2f((unsigned short)xv[6]), x7 = b2f((unsigned short)xv[7]);
        a0 += x0*w00.x + x1*w00.y + x2*w00.z + x3*w00.w
            + x4*w01.x + x5*w01.y + x6*w01.z + x7*w01.w;
        a1 += x0*w10.x + x1*w10.y + x2*w10.z + x3*w10.w
            + x4*w11.x + x5*w11.y + x6*w11.z + x7*w11.w;
      }
    }
  }
  #pragma unroll
  for (int off = 1; off <= 8; off <<= 1) {
    a0 += __shfl_xor(a0, off, 64);
    a1 += __shfl_xor(a1, off, 64);
  }
  if (cg == 0) {
    cgf[b*8192 + n]        = a0 + bc_[0];
    cgf[b*8192 + 4096 + n] = a1 + bc_[1];
  }
}

// ---------------- MFMA projection: Y = X W^T + b (fp32 W converted in staging) ----------------
// pj==0 (q) output is pre-scaled by QSCALE (compensated in chsoftmax).
__global__ __launch_bounds__(256) void proj_mfma_kernel(
    const unsigned short* __restrict__ xfb,
    const float* __restrict__ Wq, const float* __restrict__ Wk,
    const float* __restrict__ Wvc, const float* __restrict__ Wvch,
    const float* __restrict__ bq, const float* __restrict__ bk,
    const float* __restrict__ bvc, const float* __restrict__ bvch,
    unsigned short* __restrict__ q, unsigned short* __restrict__ k,
    unsigned short* __restrict__ vc, unsigned short* __restrict__ vch) {
  __shared__ __align__(16) unsigned short Ws[128][136];
  int t = threadIdx.x;
  int lane = t & 63, w = t >> 6;
  int id = lane & 15, quad = lane >> 4;
  int pj = blockIdx.y;
  int r0 = blockIdx.x*128 + w*32;

  const float* Wp = (pj == 0) ? Wq : (pj == 1) ? Wk : (pj == 2) ? Wvc : Wvch;
  for (int i = t; i < 2048; i += 256) {
    int rr = i >> 4, c8 = (i & 15) << 3;
    const float* src = Wp + rr*CH + c8;
    short8 pk;
    #pragma unroll
    for (int j = 0; j < 8; ++j) pk[j] = (short)f2bu(src[j]);
    *(short8*)&Ws[rr][c8] = pk;
  }
  short8 af[2][4];
  #pragma unroll
  for (int m = 0; m < 2; ++m)
    #pragma unroll
    for (int kc = 0; kc < 4; ++kc)
      af[m][kc] = *(const short8*)(xfb + (size_t)(r0 + m*16 + id)*CH + kc*32 + quad*8);
  __syncthreads();

  floatx4 acc[2][8];
  #pragma unroll
  for (int m = 0; m < 2; ++m)
    #pragma unroll
    for (int nt = 0; nt < 8; ++nt) acc[m][nt] = (floatx4){0.f,0.f,0.f,0.f};
  #pragma unroll
  for (int nt = 0; nt < 8; ++nt)
    #pragma unroll
    for (int kc = 0; kc < 4; ++kc) {
      short8 bf = *(const short8*)&Ws[nt*16 + id][kc*32 + quad*8];
      acc[0][nt] = __builtin_amdgcn_mfma_f32_16x16x32_bf16(af[0][kc], bf, acc[0][nt], 0, 0, 0);
      acc[1][nt] = __builtin_amdgcn_mfma_f32_16x16x32_bf16(af[1][kc], bf, acc[1][nt], 0, 0, 0);
    }

  const float* bias = (pj == 0) ? bq : (pj == 1) ? bk : (pj == 2) ? bvc : bvch;
  unsigned short* Y = (pj == 0) ? q : (pj == 1) ? k : (pj == 2) ? vc : vch;
  float osc = (pj == 0) ? QSCALE : 1.f;
  #pragma unroll
  for (int nt = 0; nt < 8; ++nt) {
    float bsv = bias[nt*16 + id];
    #pragma unroll
    for (int m = 0; m < 2; ++m)
      #pragma unroll
      for (int r = 0; r < 4; ++r) {
        int row = r0 + m*16 + quad*4 + r;
        Y[(size_t)row*CH + nt*16 + id] = f2bu((acc[m][nt][r] + bsv) * osc);
      }
  }
}

// ---------------- transpose vc (B,N,C) -> vct (B,C,N), bf16 ----------------
__global__ __launch_bounds__(256) void vtrans_kernel(const unsigned short* __restrict__ vc,
                                                     unsigned short* __restrict__ vct) {
  __shared__ unsigned short T[128][72];   // [c][n], 64 n per tile
  int t = threadIdx.x;
  int b = blockIdx.x >> 6, n0 = (blockIdx.x & 63) << 6;
  for (int i = t; i < 1024; i += 256) {
    int n = i >> 4, c0 = (i & 15) << 3;
    short8 v = *(const short8*)&vc[(size_t)(b*NSP + n0 + n)*CH + c0];
    #pragma unroll
    for (int j = 0; j < 8; ++j) T[c0+j][n] = (unsigned short)v[j];
  }
  __syncthreads();
  for (int i = t; i < 1024; i += 256) {
    int c = i >> 3, k8 = (i & 7) << 3;
    *(short8*)&vct[((size_t)b*CH + c)*NSP + n0 + k8] = *(short8*)&T[c][k8];
  }
}

// ---------------- channel scores: split-K MFMA, 64 rows/chunk. Sp[p][b][c][d] ----------------
__global__ __launch_bounds__(256) void chscore_kernel(const unsigned short* __restrict__ q,
    const unsigned short* __restrict__ k, float* __restrict__ Sp) {
  __shared__ unsigned short Qt[128][72];
  __shared__ unsigned short Kt[128][72];
  int t = threadIdx.x;
  int lane = t & 63, w = t >> 6;
  int id = lane & 15, quad = lane >> 4;
  int p = blockIdx.x;                      // 0..63, 64 n-rows each
  int b = blockIdx.y;
  const unsigned short* qb = q + (size_t)b*NSP*CH;
  const unsigned short* kb = k + (size_t)b*NSP*CH;
  int nbase = p*64;

  #pragma unroll
  for (int it = 0; it < 4; ++it) {
    int task = t + it*256;
    int c = task & 127, r0 = (task >> 7) << 3;
    short8 vq, vk;
    #pragma unroll
    for (int j = 0; j < 8; ++j) {
      size_t off = (size_t)(nbase + r0 + j)*CH + c;
      vq[j] = (short)qb[off];
      vk[j] = (short)kb[off];
    }
    *(short8*)&Qt[c][r0] = vq;
    *(short8*)&Kt[c][r0] = vk;
  }
  __syncthreads();

  floatx4 acc[2][8];
  #pragma unroll
  for (int mt = 0; mt < 2; ++mt)
    #pragma unroll
    for (int nt = 0; nt < 8; ++nt) acc[mt][nt] = (floatx4){0.f,0.f,0.f,0.f};
  #pragma unroll
  for (int kc = 0; kc < 2; ++kc) {
    short8 af0 = *(const short8*)&Qt[w*32 + id     ][kc*32 + quad*8];
    short8 af1 = *(const short8*)&Qt[w*32 + 16 + id][kc*32 + quad*8];
    #pragma unroll
    for (int nt = 0; nt < 8; ++nt) {
      short8 bf = *(const short8*)&Kt[nt*16 + id][kc*32 + quad*8];
      acc[0][nt] = __builtin_amdgcn_mfma_f32_16x16x32_bf16(af0, bf, acc[0][nt], 0, 0, 0);
      acc[1][nt] = __builtin_amdgcn_mfma_f32_16x16x32_bf16(af1, bf, acc[1][nt], 0, 0, 0);
    }
  }
  float* outp = Sp + ((size_t)(p*BATCH + b) << 14);
  #pragma unroll
  for (int mt = 0; mt < 2; ++mt)
    #pragma unroll
    for (int nt = 0; nt < 8; ++nt)
      #pragma unroll
      for (int r = 0; r < 4; ++r) {
        int c = w*32 + mt*16 + quad*4 + r;
        int d = nt*16 + id;
        outp[c*CH + d] = acc[mt][nt][r];
      }
}

// reduce split-K partials + softmax; q was pre-scaled by QSCALE so scale = 1/(64*QSCALE)
__global__ __launch_bounds__(64) void chsoftmax_kernel(const float* __restrict__ Sp,
                                                       unsigned short* __restrict__ Sb) {
  int row = blockIdx.x;
  int b = row >> 7, c = row & 127;
  int t = threadIdx.x;
  float s0 = 0.f, s1 = 0.f;
  #pragma unroll 4
  for (int p = 0; p < KCHUNKS; ++p) {
    const float* r = Sp + (((size_t)(p*BATCH + b) << 7) + c)*CH;
    s0 += r[t]; s1 += r[t+64];
  }
  const float sc = (1.f/64.f) / QSCALE;
  s0 *= sc; s1 *= sc;
  float m = fmaxf(s0, s1);
  for (int off = 32; off; off >>= 1) m = fmaxf(m, __shfl_xor(m, off, 64));
  float p0 = __expf(s0 - m), p1 = __expf(s1 - m);
  float s = p0 + p1;
  for (int off = 32; off; off >>= 1) s += __shfl_xor(s, off, 64);
  float inv = 1.f/s;
  unsigned short* r = Sb + (size_t)row*CH;
  r[t]    = f2bu(p0*inv);
  r[t+64] = f2bu(p1*inv);
}

// ---------------- channel-attention apply ----------------
__global__ __launch_bounds__(256) void chout_mfma_kernel(
    const unsigned short* __restrict__ vchb, const unsigned short* __restrict__ Sb,
    float* __restrict__ och) {
  __shared__ __align__(16) unsigned short As[128][136];
  int t = threadIdx.x;
  int lane = t & 63, w = t >> 6;
  int id = lane & 15, quad = lane >> 4;
  int b = blockIdx.x >> 5;
  int r0 = blockIdx.x*128 + w*32;

  const unsigned short* Sp = Sb + ((size_t)b << 14);
  for (int i = t; i < 2048; i += 256) {
    int rr = i >> 4, c8 = (i & 15) << 3;
    *(short8*)&As[rr][c8] = *(const short8*)(Sp + rr*CH + c8);
  }
  short8 af[2][4];
  #pragma unroll
  for (int m = 0; m < 2; ++m)
    #pragma unroll
    for (int kc = 0; kc < 4; ++kc)
      af[m][kc] = *(const short8*)(vchb + (size_t)(r0 + m*16 + id)*CH + kc*32 + quad*8);
  __syncthreads();

  floatx4 acc[2][8];
  #pragma unroll
  for (int m = 0; m < 2; ++m)
    #pragma unroll
    for (int nt = 0; nt < 8; ++nt) acc[m][nt] = (floatx4){0.f,0.f,0.f,0.f};
  #pragma unroll
  for (int nt = 0; nt < 8; ++nt)
    #pragma unroll
    for (int kc = 0; kc < 4; ++kc) {
      short8 bf = *(const short8*)&As[nt*16 + id][kc*32 + quad*8];
      acc[0][nt] = __builtin_amdgcn_mfma_f32_16x16x32_bf16(af[0][kc], bf, acc[0][nt], 0, 0, 0);
      acc[1][nt] = __builtin_amdgcn_mfma_f32_16x16x32_bf16(af[1][kc], bf, acc[1][nt], 0, 0, 0);
    }
  #pragma unroll
  for (int nt = 0; nt < 8; ++nt)
    #pragma unroll
    for (int m = 0; m < 2; ++m)
      #pragma unroll
      for (int r = 0; r < 4; ++r) {
        int row = r0 + m*16 + quad*4 + r;
        och[(size_t)row*CH + nt*16 + id] = acc[m][nt][r];
      }
}

// ---------------- flash partial: split-K x4, register-pipelined (R9-exact structure) ----------------
// q pre-scaled by QSCALE at projection, so p = exp(s) directly.
__global__ __launch_bounds__(256) void flash_part_kernel(
    const unsigned short* __restrict__ Qg, const unsigned short* __restrict__ Kg,
    const unsigned short* __restrict__ Vtg,
    unsigned short* __restrict__ Opart, float* __restrict__ lpart) {
  __shared__ __align__(16) unsigned short Ks[64][136];
  __shared__ __align__(16) unsigned short Vt[128][72];
  __shared__ __align__(16) unsigned short Ps[4][32][68];
  int t = threadIdx.x;
  int lane = t & 63, w = t >> 6;
  int id = lane & 15, quad = lane >> 4;
  int blk = blockIdx.x;
  int x = blk & 7, y = blk >> 3;
  int tile = y & 31;
  int b = x >> 1;
  int ks = (x & 1) + ((y >> 5) << 1);    // 0..3
  int n0 = tile << 7;
  int r0 = n0 + w*32;

  const unsigned short* Qb = Qg  + (size_t)b*NSP*CH;
  const unsigned short* Kb = Kg  + (size_t)b*NSP*CH;
  const unsigned short* Vb = Vtg + (size_t)b*CH*NSP;

  int kr[4], kc8[4], vr[4], vn[4];
  #pragma unroll
  for (int it = 0; it < 4; ++it) {
    int task = t + it*256;
    kr[it] = task >> 4; kc8[it] = (task & 15) << 3;
    vr[it] = task >> 3; vn[it]  = (task & 7) << 3;
  }

  short8 qf[2][4];
  #pragma unroll
  for (int m = 0; m < 2; ++m)
    #pragma unroll
    for (int kc = 0; kc < 4; ++kc)
      qf[m][kc] = *(const short8*)(Qb + (size_t)(r0 + m*16 + id)*CH + kc*32 + quad*8);

  floatx4 O[2][8];
  #pragma unroll
  for (int m = 0; m < 2; ++m)
    #pragma unroll
    for (int ct = 0; ct < 8; ++ct) O[m][ct] = (floatx4){0.f,0.f,0.f,0.f};
  float lrun[2][4];
  #pragma unroll
  for (int m = 0; m < 2; ++m)
    #pragma unroll
    for (int r = 0; r < 4; ++r) lrun[m][r] = 0.f;

  short8 kreg[4], vreg[4];
  {
    int kbase = ks*1024;
    #pragma unroll
    for (int it = 0; it < 4; ++it) {
      kreg[it] = *(const short8*)(Kb + (size_t)(kbase + kr[it])*CH + kc8[it]);
      vreg[it] = *(const short8*)(Vb + (size_t)vr[it]*NSP + kbase + vn[it]);
    }
  }

  for (int kt = 0; kt < 16; ++kt) {
    __syncthreads();
    #pragma unroll
    for (int it = 0; it < 4; ++it) {
      *(short8*)&Ks[kr[it]][kc8[it]] = kreg[it];
      *(short8*)&Vt[vr[it]][vn[it]]  = vreg[it];
    }
    __syncthreads();
    if (kt < 15) {
      int kbase = ks*1024 + (kt+1)*64;
      #pragma unroll
      for (int it = 0; it < 4; ++it) {
        kreg[it] = *(const short8*)(Kb + (size_t)(kbase + kr[it])*CH + kc8[it]);
        vreg[it] = *(const short8*)(Vb + (size_t)vr[it]*NSP + kbase + vn[it]);
      }
    }

    floatx4 S[2][4];
    #pragma unroll
    for (int nt = 0; nt < 4; ++nt) {
      floatx4 a0 = (floatx4){0.f,0.f,0.f,0.f};
      floatx4 a1 = (floatx4){0.f,0.f,0.f,0.f};
      #pragma unroll
      for (int kc = 0; kc < 4; ++kc) {
        short8 kf = *(const short8*)&Ks[nt*16 + id][kc*32 + quad*8];
        a0 = __builtin_amdgcn_mfma_f32_16x16x32_bf16(qf[0][kc], kf, a0, 0, 0, 0);
        a1 = __builtin_amdgcn_mfma_f32_16x16x32_bf16(qf[1][kc], kf, a1, 0, 0, 0);
      }
      S[0][nt] = a0; S[1][nt] = a1;
    }
    #pragma unroll
    for (int m = 0; m < 2; ++m) {
      float rs[4] = {0.f,0.f,0.f,0.f};
      #pragma unroll
      for (int nt = 0; nt < 4; ++nt)
        #pragma unroll
        for (int r = 0; r < 4; ++r) {
          float p = __expf(S[m][nt][r]);
          rs[r] += p;
          Ps[w][m*16 + quad*4 + r][nt*16 + id] = f2bu(p);
        }
      #pragma unroll
      for (int off = 1; off <= 8; off <<= 1)
        #pragma unroll
        for (int r = 0; r < 4; ++r) rs[r] += __shfl_xor(rs[r], off, 64);
      #pragma unroll
      for (int r = 0; r < 4; ++r) lrun[m][r] += rs[r];
    }
    #pragma unroll
    for (int nc = 0; nc < 2; ++nc) {
      short8 pf0 = *(const short8*)&Ps[w][id     ][nc*32 + quad*8];
      short8 pf1 = *(const short8*)&Ps[w][16 + id][nc*32 + quad*8];
      #pragma unroll
      for (int ct = 0; ct < 8; ++ct) {
        short8 vf = *(const short8*)&Vt[ct*16 + id][nc*32 + quad*8];
        O[0][ct] = __builtin_amdgcn_mfma_f32_16x16x32_bf16(pf0, vf, O[0][ct], 0, 0, 0);
        O[1][ct] = __builtin_amdgcn_mfma_f32_16x16x32_bf16(pf1, vf, O[1][ct], 0, 0, 0);
      }
    }
  }

  unsigned short* Op = Opart + (size_t)ks*BIG + (size_t)b*NSP*CH;
  #pragma unroll
  for (int m = 0; m < 2; ++m)
    #pragma unroll
    for (int ct = 0; ct < 8; ++ct)
      #pragma unroll
      for (int r = 0; r < 4; ++r) {
        int row = r0 + m*16 + quad*4 + r;
        Op[(size_t)row*CH + ct*16 + id] = f2bu(O[m][ct][r]);
      }
  if (id == 0) {
    float* lp = lpart + (size_t)ks*BATCH*NSP + (size_t)b*NSP;
    #pragma unroll
    for (int m = 0; m < 2; ++m)
      #pragma unroll
      for (int r = 0; r < 4; ++r)
        lp[r0 + m*16 + quad*4 + r] = lrun[m][r];
  }
}

// ---------------- fused combine + gate + output: out = x + (w0*oc + w2*och)^T ----------------
__global__ __launch_bounds__(256) void fuse_kernel(const float* __restrict__ x,
    const unsigned short* __restrict__ Opart, const float* __restrict__ lpart,
    const float* __restrict__ och, const float* __restrict__ pooled,
    const float* __restrict__ Wg, const float* __restrict__ bg,
    float* __restrict__ out) {
  __shared__ float T[128][65];
  __shared__ float linv[64];
  __shared__ float wsh[2];
  int t = threadIdx.x;
  int b  = blockIdx.x >> 6;
  int n0 = (blockIdx.x & 63) << 6;
  if (t < 64) {
    float l = 0.f;
    #pragma unroll
    for (int p = 0; p < FKSPLIT; ++p)
      l += lpart[(size_t)p*BATCH*NSP + b*NSP + n0 + t];
    linv[t] = 1.f / l;
    // gate: 3 dots of pooled[b] with Wg rows, lane-parallel + shuffle reduce
    float p0 = pooled[b*CH + t], p1 = pooled[b*CH + 64 + t];
    float d0 = p0*Wg[t]       + p1*Wg[64 + t];
    float d1 = p0*Wg[128 + t] + p1*Wg[192 + t];
    float d2 = p0*Wg[256 + t] + p1*Wg[320 + t];
    #pragma unroll
    for (int off = 32; off; off >>= 1) {
      d0 += __shfl_xor(d0, off, 64);
      d1 += __shfl_xor(d1, off, 64);
      d2 += __shfl_xor(d2, off, 64);
    }
    if (t == 0) {
      d0 += bg[0]; d1 += bg[1]; d2 += bg[2];
      float m = fmaxf(d0, fmaxf(d1, d2));
      float e0 = __expf(d0 - m), e1 = __expf(d1 - m), e2 = __expf(d2 - m);
      float inv = 1.f/(e0 + e1 + e2);
      wsh[0] = e0*inv;     // w0
      wsh[1] = e2*inv;     // w2
    }
  }
  __syncthreads();
  float w0 = wsh[0], w2 = wsh[1];
  const float* ochb = och + (size_t)(b*NSP + n0)*CH;
  for (int i = t; i < 8192; i += 256) {
    int n = i >> 7, c = i & 127;
    size_t oidx = (size_t)(b*NSP + n0 + n)*CH + c;
    float o = 0.f;
    #pragma unroll
    for (int p = 0; p < FKSPLIT; ++p) o += b2f(Opart[(size_t)p*BIG + oidx]);
    T[c][n] = w0*o*linv[n] + w2*ochb[(size_t)n*CH + c];
  }
  __syncthreads();
  for (int i = t; i < 8192; i += 256) {
    int c = i >> 6, n = i & 63;
    size_t idx = (size_t)(b*CH + c)*NSP + n0 + n;
    out[idx] = x[idx] + T[c][n];
  }
}

extern "C" void kernel_launch(void* const* d_in, const int* in_sizes, int n_in,
                              void* d_out, int out_size, void* d_ws, size_t ws_size,
                              hipStream_t stream) {
  (void)in_sizes; (void)n_in; (void)out_size; (void)ws_size;
  const float* x     = (const float*)d_in[0];
  const float* ln_g  = (const float*)d_in[1];
  const float* ln_b  = (const float*)d_in[2];
  const float* Wq    = (const float*)d_in[3];
  const float* bq    = (const float*)d_in[4];
  const float* Wk    = (const float*)d_in[5];
  const float* bk    = (const float*)d_in[6];
  const float* Wvc   = (const float*)d_in[7];
  const float* bvc   = (const float*)d_in[8];
  const float* Wvch  = (const float*)d_in[9];
  const float* bvch  = (const float*)d_in[10];
  const float* Wconv = (const float*)d_in[11];
  const float* bconv = (const float*)d_in[12];
  const float* Wg    = (const float*)d_in[13];
  const float* bg    = (const float*)d_in[14];

  float* out = (float*)d_out;
  float* cgf = out + (size_t)BIG;

  char* base = (char*)d_ws;
  float* och  = (float*)(base);                    // 0..8 MB: out_channel (fp32)
  // 8..24 MB: Opart (4 x 4 MB bf16), overlaying Sp (16 MB @8, dead after chsoftmax).
  // vcb @24 is dead after vtrans.
  unsigned short* Opart = (unsigned short*)(base + 8*(size_t)MB);
  float* Sp             = (float*)(base + 8*(size_t)MB);            // 16 MB
  unsigned short* vcb   = (unsigned short*)(base + 24*(size_t)MB);  // 4 MB
  float* lpart  = (float*)(base + 32*(size_t)MB);                   // 256 KB
  unsigned short* Schb = (unsigned short*)(base + 32*(size_t)MB + 512*1024); // 128 KB
  float* pooled = (float*)(base + 32*(size_t)MB + 768*1024);
  unsigned short* qb   = (unsigned short*)(base + 33*(size_t)MB);   // 4 MB
  unsigned short* kb   = (unsigned short*)(base + 37*(size_t)MB);   // 4 MB
  unsigned short* vct  = (unsigned short*)(base + 41*(size_t)MB);   // 4 MB
  unsigned short* vchb = (unsigned short*)(base + 45*(size_t)MB);   // 4 MB
  unsigned short* xfb  = (unsigned short*)(base + 49*(size_t)MB);   // 4 MB, ends 53 MB

  ln_kernel     <<<256, 256, 0, stream>>>(x, ln_g, ln_b, xfb);
  pooled_kernel <<<512, 256, 0, stream>>>(x, pooled);
  conv_kernel   <<<1024, 256, 0, stream>>>(xfb, Wconv, bconv, cgf);
  proj_mfma_kernel<<<dim3(128,4), 256, 0, stream>>>(xfb, Wq, Wk, Wvc, Wvch,
                                                    bq, bk, bvc, bvch,
                                                    qb, kb, vcb, vchb);
  vtrans_kernel <<<256, 256, 0, stream>>>(vcb, vct);
  chscore_kernel<<<dim3(KCHUNKS, BATCH), 256, 0, stream>>>(qb, kb, Sp);
  chsoftmax_kernel<<<512, 64, 0, stream>>>(Sp, Schb);
  chout_mfma_kernel<<<128, 256, 0, stream>>>(vchb, Schb, och);
  flash_part_kernel<<<512, 256, 0, stream>>>(qb, kb, vct, Opart, lpart);
  fuse_kernel   <<<256, 256, 0, stream>>>(x, Opart, lpart, och, pooled, Wg, bg, out);
}